// Round 6
// baseline (434.365 us; speedup 1.0000x reference)
//
#include <hip/hip_runtime.h>
#include <hip/hip_bf16.h>
#include <math.h>

// Problem constants: S=8192, B=4, C=512, H=8, D=64
#define S_LEN 8192
#define BATCH 4
#define CDIM  512
#define HEADS 8
#define DDIM  64
#define MROWS (S_LEN * BATCH)   // 32768 rows; row m = s*BATCH + b; layout [S,B,C]
#define EPS_F 1e-6f

typedef __attribute__((ext_vector_type(8))) short     short8_t;
typedef __attribute__((ext_vector_type(4))) float     f32x4;
typedef unsigned short ushort_t;
typedef __attribute__((ext_vector_type(4))) unsigned short ushort4_t;
typedef __attribute__((ext_vector_type(8))) unsigned short ushort8_t;

static __device__ __forceinline__ ushort_t f2bf(float f) {
  __hip_bfloat16 h = __float2bfloat16(f);   // RNE
  return *(ushort_t*)&h;
}

// Async global->LDS, 16B per lane. LDS dest = wave-uniform base + lane*16.
static __device__ __forceinline__ void gl2lds16(const ushort_t* g, ushort_t* l) {
  __builtin_amdgcn_global_load_lds((const __attribute__((address_space(1))) void*)g,
                                   (__attribute__((address_space(3))) void*)l,
                                   16, 0, 0);
}

// ---------------------------------------------------------------------------
// Weights fp32 -> bf16 (4 MB total, ~3 us)
// ---------------------------------------------------------------------------
__global__ __launch_bounds__(256)
void cvtW_kernel(const float* __restrict__ a, const float* __restrict__ b,
                 const float* __restrict__ c, const float* __restrict__ d,
                 ushort_t* __restrict__ oa, ushort_t* __restrict__ ob,
                 ushort_t* __restrict__ oc, ushort_t* __restrict__ od) {
  const float* src = (blockIdx.y == 0) ? a : (blockIdx.y == 1) ? b :
                     (blockIdx.y == 2) ? c : d;
  ushort_t* dst    = (blockIdx.y == 0) ? oa : (blockIdx.y == 1) ? ob :
                     (blockIdx.y == 2) ? oc : od;
  const size_t i = ((size_t)blockIdx.x * 256 + threadIdx.x) * 8;
  const float4 x = *(const float4*)&src[i];
  const float4 y = *(const float4*)&src[i + 4];
  ushort8_t p;
  p[0] = f2bf(x.x); p[1] = f2bf(x.y); p[2] = f2bf(x.z); p[3] = f2bf(x.w);
  p[4] = f2bf(y.x); p[5] = f2bf(y.y); p[6] = f2bf(y.z); p[7] = f2bf(y.w);
  *(ushort8_t*)&dst[i] = p;
}

// ---------------------------------------------------------------------------
// Direct-to-register MFMA GEMM (no LDS, no barriers):
//   Y[m][n] = act( sum_k A[m][k]*BT[n][k] + bias[n] )
// BM=BN=128, 256 thr = 4 waves in 2x2; wave = 64x64 via 4x4 frags of
// 16x16x32 bf16 MFMA. Every fragment is private to its wave: lane l of
// frag i holds row (i*16 + (l&15)), k-slice (l>>4)*8..+8 — a contiguous
// 16B (bf16) or 32B (fp32->cvt) load straight from global. B (weights,
// 512KB) is L2-resident; A re-reads across 4 n-tiles hit L3.
// 2-deep named-stage prefetch (static indexing only).
// AF32: A is fp32 (cvt in-reg); ACT: elu(x)+1; OUTF32: fp32 output.
// ---------------------------------------------------------------------------
template<int ACT, int AF32, int OUTF32>
__global__ __launch_bounds__(256)
void gemm_direct(const void* __restrict__ Av, const ushort_t* __restrict__ BT,
                 const float* __restrict__ bias, void* __restrict__ Yv) {
  const int t    = threadIdx.x;
  const int m0   = blockIdx.x * 128;
  const int n0   = blockIdx.y * 128;
  const int w    = t >> 6;
  const int lane = t & 63;
  const int wm   = (w >> 1) * 64;
  const int wn   = (w & 1) * 64;
  const int lr   = lane & 15;
  const int lk   = (lane >> 4) * 8;

  const float*    Af = (const float*)Av;
  const ushort_t* Ah = (const ushort_t*)Av;

  size_t arow[4], brow[4];
  #pragma unroll
  for (int i = 0; i < 4; ++i) {
    arow[i] = (size_t)(m0 + wm + i * 16 + lr) * CDIM + lk;
    brow[i] = (size_t)(n0 + wn + i * 16 + lr) * CDIM + lk;
  }

  f32x4 acc[4][4];
  #pragma unroll
  for (int mi = 0; mi < 4; ++mi)
    #pragma unroll
    for (int ni = 0; ni < 4; ++ni)
      acc[mi][ni] = (f32x4){0.f, 0.f, 0.f, 0.f};

  // two named prefetch stages (rule #20: static indexing only)
  float4 aS0[4][2], aS1[4][2];
  short8_t hS0[4], hS1[4];
  short8_t bS0[4], bS1[4];

  auto loadStage = [&](float4 (&a)[4][2], short8_t (&hh)[4], short8_t (&bb)[4],
                       int kt) {
    #pragma unroll
    for (int i = 0; i < 4; ++i) {
      if (AF32) {
        a[i][0] = *(const float4*)&Af[arow[i] + kt];
        a[i][1] = *(const float4*)&Af[arow[i] + kt + 4];
      } else {
        hh[i] = *(const short8_t*)&Ah[arow[i] + kt];
      }
      bb[i] = *(const short8_t*)&BT[brow[i] + kt];
    }
  };

  auto computeStage = [&](float4 (&a)[4][2], short8_t (&hh)[4],
                          short8_t (&bb)[4]) {
    short8_t af[4];
    #pragma unroll
    for (int mi = 0; mi < 4; ++mi) {
      if (AF32) {
        short8_t v;
        v[0] = (short)f2bf(a[mi][0].x); v[1] = (short)f2bf(a[mi][0].y);
        v[2] = (short)f2bf(a[mi][0].z); v[3] = (short)f2bf(a[mi][0].w);
        v[4] = (short)f2bf(a[mi][1].x); v[5] = (short)f2bf(a[mi][1].y);
        v[6] = (short)f2bf(a[mi][1].z); v[7] = (short)f2bf(a[mi][1].w);
        af[mi] = v;
      } else {
        af[mi] = hh[mi];
      }
    }
    #pragma unroll
    for (int mi = 0; mi < 4; ++mi)
      #pragma unroll
      for (int ni = 0; ni < 4; ++ni)
        acc[mi][ni] = __builtin_amdgcn_mfma_f32_16x16x32_bf16(
            af[mi], bb[ni], acc[mi][ni], 0, 0, 0);
  };

  loadStage(aS0, hS0, bS0, 0);
  #pragma unroll
  for (int kk = 0; kk < CDIM / 64; ++kk) {
    const int kt = kk * 64;
    if (kt + 32 < CDIM) loadStage(aS1, hS1, bS1, kt + 32);
    computeStage(aS0, hS0, bS0);
    if (kt + 64 < CDIM) loadStage(aS0, hS0, bS0, kt + 64);
    computeStage(aS1, hS1, bS1);
  }

  // epilogue: C layout col=lane&15, row=(lane>>4)*4+r (verified r2)
  float* Yf = (float*)Yv;
  ushort_t* Yh = (ushort_t*)Yv;
  float bi[4];
  int coln[4];
  #pragma unroll
  for (int ni = 0; ni < 4; ++ni) {
    coln[ni] = n0 + wn + ni * 16 + lr;
    bi[ni]   = bias[coln[ni]];
  }
  #pragma unroll
  for (int mi = 0; mi < 4; ++mi) {
    #pragma unroll
    for (int r = 0; r < 4; ++r) {
      const int m = m0 + wm + mi * 16 + (lane >> 4) * 4 + r;
      #pragma unroll
      for (int ni = 0; ni < 4; ++ni) {
        float v = acc[mi][ni][r] + bi[ni];
        if (ACT) v = (v > 0.f) ? (v + 1.f) : expf(v);
        const size_t o = (size_t)m * CDIM + coln[ni];
        if (OUTF32) Yf[o] = v;
        else        Yh[o] = f2bf(v);
      }
    }
  }
}

// ---------------------------------------------------------------------------
// kv GEMM: per (b,h), kv[d][f] = sum_s k[s][d]*v[s][f], ksum[d] = sum_s k[s][d].
// Split-K: grid (32 bh, 16 chunks of 512 s). Reg-staged transpose into
// fragment-packed LDS (A = k^T, B = v); ksum via ones-B-fragment MFMA.
// ---------------------------------------------------------------------------
__global__ __launch_bounds__(256)
void gemm_kv(const ushort_t* __restrict__ Kb, const ushort_t* __restrict__ Vb,
             float* __restrict__ kvpart, float* __restrict__ ksumpart) {
  __shared__ __align__(16) ushort_t klds[8192];
  __shared__ __align__(16) ushort_t vlds[8192];
  const int bh    = blockIdx.x;
  const int chunk = blockIdx.y;
  const int b = bh >> 3, h = bh & 7;
  const int t = threadIdx.x;
  const int w = t >> 6;
  const int lane = t & 63;

  f32x4 acc[4];
  #pragma unroll
  for (int fg = 0; fg < 4; ++fg) acc[fg] = (f32x4){0.f, 0.f, 0.f, 0.f};
  f32x4 accs = (f32x4){0.f, 0.f, 0.f, 0.f};

  short8_t ones;
  #pragma unroll
  for (int i = 0; i < 8; ++i) ones[i] = (short)0x3F80;

  for (int round = 0; round < 4; ++round) {
    const int sbase = chunk * 512 + round * 128;
    __syncthreads();
    #pragma unroll
    for (int i = 0; i < 4; ++i) {
      const int idx  = i * 256 + t;
      const int sl   = idx >> 3;
      const int d8   = idx & 7;
      const size_t src = (size_t)((sbase + sl) * BATCH + b) * CDIM + h * DDIM + d8 * 8;
      const ushort8_t kp = *(const ushort8_t*)&Kb[src];
      const ushort8_t vp = *(const ushort8_t*)&Vb[src];
      const int sb  = sl >> 5;
      const int j   = sl & 7;
      const int lp0 = (d8 & 1) * 8 + ((sl >> 3) & 3) * 16;
      const int dg  = d8 >> 1;
      const int kbase = ((sb * 4 + dg) * 64 + lp0) * 8 + j;
      #pragma unroll
      for (int e = 0; e < 8; ++e) {
        klds[kbase + e * 8] = kp[e];
        vlds[kbase + e * 8] = vp[e];
      }
    }
    __syncthreads();
    #pragma unroll
    for (int sb = 0; sb < 4; ++sb) {
      const short8_t af = *(const short8_t*)&klds[((sb * 4 + w) * 64 + lane) * 8];
      accs = __builtin_amdgcn_mfma_f32_16x16x32_bf16(af, ones, accs, 0, 0, 0);
      #pragma unroll
      for (int fg = 0; fg < 4; ++fg) {
        const short8_t bf = *(const short8_t*)&vlds[((sb * 4 + fg) * 64 + lane) * 8];
        acc[fg] = __builtin_amdgcn_mfma_f32_16x16x32_bf16(af, bf, acc[fg], 0, 0, 0);
      }
    }
  }

  const size_t obase = ((size_t)bh * 16 + chunk) * 64;
  #pragma unroll
  for (int fg = 0; fg < 4; ++fg)
    #pragma unroll
    for (int r = 0; r < 4; ++r) {
      const int d = w * 16 + (lane >> 4) * 4 + r;
      kvpart[(obase + d) * 64 + fg * 16 + (lane & 15)] = acc[fg][r];
    }
  if ((lane & 15) == 0) {
    #pragma unroll
    for (int r = 0; r < 4; ++r)
      ksumpart[obase + w * 16 + (lane >> 4) * 4 + r] = accs[r];
  }
}

// ---------------------------------------------------------------------------
__global__ __launch_bounds__(256)
void kv_finish(const float* __restrict__ kvpart, const float* __restrict__ ksumpart,
               ushort_t* __restrict__ kvT) {
  const int bh = blockIdx.x;
  const int t  = threadIdx.x;
  for (int idx = t; idx < 4096; idx += 256) {
    const int d = idx >> 6, f = idx & 63;
    float s = 0.f;
    for (int c = 0; c < 16; ++c)
      s += kvpart[(((size_t)bh * 16 + c) * 64 + d) * 64 + f];
    kvT[((size_t)bh * 80 + f) * 64 + d] = f2bf(s);
  }
  if (t < 64) {
    float s = 0.f;
    for (int c = 0; c < 16; ++c)
      s += ksumpart[((size_t)bh * 16 + c) * 64 + t];
    kvT[((size_t)bh * 80 + 64) * 64 + t] = f2bf(s);
  }
  for (int i = t; i < 15 * 64; i += 256)
    kvT[((size_t)bh * 80 + 65) * 64 + i] = 0;
}

// ---------------------------------------------------------------------------
// qkv GEMM: y = (q @ kv) / (q . ksum + eps); B = kvT_pad [80][64], col 64 = denom.
// ---------------------------------------------------------------------------
__global__ __launch_bounds__(256)
void gemm_qkv(ushort_t* __restrict__ Qb, const ushort_t* __restrict__ kvT) {
  __shared__ __align__(16) ushort_t alds[8192];
  __shared__ __align__(16) ushort_t blds[5120];
  const int bh    = blockIdx.x;
  const int chunk = blockIdx.y;
  const int b = bh >> 3, h = bh & 7;
  const int t = threadIdx.x;
  const int w = t >> 6;
  const int lane = t & 63;
  const int lr = lane & 15;
  const int lk = (lane >> 4) * 8;

  #pragma unroll
  for (int i = 0; i < 4; ++i) {
    const int fidx = w * 4 + i;
    const int ks = fidx >> 3, fm = fidx & 7;
    const ushort_t* src = Qb +
        (size_t)((chunk * 128 + fm * 16 + lr) * BATCH + b) * CDIM +
        h * DDIM + ks * 32 + lk;
    gl2lds16(src, &alds[fidx * 512]);
  }
  for (int idx = w; idx < 10; idx += 4) {
    const int ks = idx / 5, fg = idx % 5;
    const ushort_t* src = kvT + (size_t)(bh * 80 + fg * 16 + lr) * 64 + ks * 32 + lk;
    gl2lds16(src, &blds[idx * 512]);
  }
  __syncthreads();

  f32x4 acc[2][5];
  #pragma unroll
  for (int mi = 0; mi < 2; ++mi)
    #pragma unroll
    for (int fg = 0; fg < 5; ++fg)
      acc[mi][fg] = (f32x4){0.f, 0.f, 0.f, 0.f};

  #pragma unroll
  for (int ks = 0; ks < 2; ++ks) {
    short8_t af[2], bf[5];
    #pragma unroll
    for (int mi = 0; mi < 2; ++mi)
      af[mi] = *(const short8_t*)&alds[(ks * 8 + w * 2 + mi) * 512 + lane * 8];
    #pragma unroll
    for (int fg = 0; fg < 5; ++fg)
      bf[fg] = *(const short8_t*)&blds[(ks * 5 + fg) * 512 + lane * 8];
    #pragma unroll
    for (int mi = 0; mi < 2; ++mi)
      #pragma unroll
      for (int fg = 0; fg < 5; ++fg)
        acc[mi][fg] = __builtin_amdgcn_mfma_f32_16x16x32_bf16(
            af[mi], bf[fg], acc[mi][fg], 0, 0, 0);
  }

  #pragma unroll
  for (int mi = 0; mi < 2; ++mi) {
    #pragma unroll
    for (int r = 0; r < 4; ++r) {
      const float dv  = __shfl(acc[mi][4][r], lane & 48);
      const float inv = 1.f / (dv + EPS_F);
      const int s = chunk * 128 + w * 32 + mi * 16 + (lane >> 4) * 4 + r;
      const size_t rowb = (size_t)(s * BATCH + b) * CDIM + h * DDIM;
      #pragma unroll
      for (int fg = 0; fg < 4; ++fg)
        Qb[rowb + fg * 16 + lr] = f2bf(acc[mi][fg][r] * inv);
    }
  }
}

// ---------------------------------------------------------------------------
extern "C" void kernel_launch(void* const* d_in, const int* in_sizes, int n_in,
                              void* d_out, int out_size, void* d_ws, size_t ws_size,
                              hipStream_t stream) {
  const float* q_in = (const float*)d_in[0];
  const float* k_in = (const float*)d_in[1];
  const float* v_in = (const float*)d_in[2];
  const float* Wq   = (const float*)d_in[3];
  const float* bq   = (const float*)d_in[4];
  const float* Wk   = (const float*)d_in[5];
  const float* bk   = (const float*)d_in[6];
  const float* Wv   = (const float*)d_in[7];
  const float* bv   = (const float*)d_in[8];
  const float* Wp   = (const float*)d_in[9];
  const float* bp   = (const float*)d_in[10];
  float* out = (float*)d_out;

  const size_t NTOK = (size_t)MROWS * CDIM;      // 16,777,216 elems
  const size_t NW   = (size_t)CDIM * CDIM;       // 262,144
  ushort_t* Wq_bf  = (ushort_t*)d_ws;
  ushort_t* Wk_bf  = Wq_bf + NW;
  ushort_t* Wv_bf  = Wk_bf + NW;
  ushort_t* Wp_bf  = Wv_bf + NW;
  ushort_t* qbuf   = Wp_bf + NW;
  ushort_t* kbuf   = qbuf + NTOK;
  ushort_t* vbuf   = kbuf + NTOK;
  ushort_t* kvT    = vbuf + NTOK;                           // 32*80*64
  float* kvpart    = (float*)(kvT + (size_t)32 * 80 * 64);  // 512*64*64
  float* ksumpart  = kvpart + (size_t)512 * 64 * 64;        // 512*64

  const dim3 blk(256);

  // 1) Weights fp32 -> bf16
  cvtW_kernel<<<dim3(128, 4), blk, 0, stream>>>(Wq, Wk, Wv, Wp,
                                                Wq_bf, Wk_bf, Wv_bf, Wp_bf);

  // 2) Projections: direct-to-reg MFMA (fp32 A cvt in-reg; ELU+1 for Q,K)
  const dim3 gmm(MROWS / 128, CDIM / 128);   // (256, 4)
  gemm_direct<1, 1, 0><<<gmm, blk, 0, stream>>>(q_in, Wq_bf, bq, qbuf);
  gemm_direct<1, 1, 0><<<gmm, blk, 0, stream>>>(k_in, Wk_bf, bk, kbuf);
  gemm_direct<0, 1, 0><<<gmm, blk, 0, stream>>>(v_in, Wv_bf, bv, vbuf);

  // 3) kv = sum_s k^T v (+ ksum via ones-MFMA), split-K then finish
  gemm_kv<<<dim3(32, 16), blk, 0, stream>>>(kbuf, vbuf, kvpart, ksumpart);
  kv_finish<<<dim3(32), blk, 0, stream>>>(kvpart, ksumpart, kvT);

  // 4) y = (q @ kv) / (q . ksum + eps), bf16 in place over q buffer
  gemm_qkv<<<dim3(32, 64), blk, 0, stream>>>(qbuf, kvT);

  // 5) Output projection: bf16 A direct -> fp32 d_out
  gemm_direct<0, 0, 1><<<gmm, blk, 0, stream>>>(qbuf, Wp_bf, bp, out);
}

// Round 7
// 263.545 us; speedup vs baseline: 1.6482x; 1.6482x over previous
//
#include <hip/hip_runtime.h>
#include <hip/hip_bf16.h>
#include <math.h>

// Problem constants: S=8192, B=4, C=512, H=8, D=64
#define S_LEN 8192
#define BATCH 4
#define CDIM  512
#define HEADS 8
#define DDIM  64
#define MROWS (S_LEN * BATCH)   // 32768 rows; row m = s*BATCH + b; layout [S,B,C]
#define EPS_F 1e-6f

typedef __attribute__((ext_vector_type(8))) short     short8_t;
typedef __attribute__((ext_vector_type(4))) float     f32x4;
typedef unsigned short ushort_t;
typedef __attribute__((ext_vector_type(4))) unsigned short ushort4_t;
typedef __attribute__((ext_vector_type(8))) unsigned short ushort8_t;

static __device__ __forceinline__ ushort_t f2bf(float f) {
  __hip_bfloat16 h = __float2bfloat16(f);   // RNE
  return *(ushort_t*)&h;
}

// Async global->LDS, 16B per lane. LDS dest = wave-uniform base + lane*16.
static __device__ __forceinline__ void gl2lds16(const ushort_t* g, ushort_t* l) {
  __builtin_amdgcn_global_load_lds((const __attribute__((address_space(1))) void*)g,
                                   (__attribute__((address_space(3))) void*)l,
                                   16, 0, 0);
}

// ---------------------------------------------------------------------------
// Weights fp32 -> bf16 (4 MB total, ~3 us)
// ---------------------------------------------------------------------------
__global__ __launch_bounds__(256)
void cvtW_kernel(const float* __restrict__ a, const float* __restrict__ b,
                 const float* __restrict__ c, const float* __restrict__ d,
                 ushort_t* __restrict__ oa, ushort_t* __restrict__ ob,
                 ushort_t* __restrict__ oc, ushort_t* __restrict__ od) {
  const float* src = (blockIdx.y == 0) ? a : (blockIdx.y == 1) ? b :
                     (blockIdx.y == 2) ? c : d;
  ushort_t* dst    = (blockIdx.y == 0) ? oa : (blockIdx.y == 1) ? ob :
                     (blockIdx.y == 2) ? oc : od;
  const size_t i = ((size_t)blockIdx.x * 256 + threadIdx.x) * 8;
  const float4 x = *(const float4*)&src[i];
  const float4 y = *(const float4*)&src[i + 4];
  ushort8_t p;
  p[0] = f2bf(x.x); p[1] = f2bf(x.y); p[2] = f2bf(x.z); p[3] = f2bf(x.w);
  p[4] = f2bf(y.x); p[5] = f2bf(y.y); p[6] = f2bf(y.z); p[7] = f2bf(y.w);
  *(ushort8_t*)&dst[i] = p;
}

// ---------------------------------------------------------------------------
// Fused Q/K/V projection GEMM, double-buffered LDS, ONE barrier per K-step
// (T3 minimum-2-phase + T14 issue-early/write-late for the fp32 A operand).
//   Y[m][n] = act( sum_k X[m][k]*W[n][k] + bias[n] ), act = elu+1 for z<2.
// BM=BN=128, BK=32, 256 thr = 4 waves 2x2; wave = 64x64 via 4x4 frags of
// 16x16x32 bf16 MFMA. LDS fragment-packed (frag = 64 lanes x 16B) ->
// conflict-free ds_write_b64 staging and ds_read_b128 fragment loads.
// A: fp32 global->reg (issued one iter early) -> cvt -> ds_write.
// B: bf16 weights via global_load_lds (L2-resident).
// gridDim.z = 3 selects {q,k,v}: all three GEMMs co-scheduled in one launch.
// ---------------------------------------------------------------------------
__global__ __launch_bounds__(256)
void gemm_proj3(const float* __restrict__ Xq, const float* __restrict__ Xk,
                const float* __restrict__ Xv,
                const ushort_t* __restrict__ Wq, const ushort_t* __restrict__ Wk,
                const ushort_t* __restrict__ Wv,
                const float* __restrict__ bq, const float* __restrict__ bk,
                const float* __restrict__ bv,
                ushort_t* __restrict__ Yq, ushort_t* __restrict__ Yk,
                ushort_t* __restrict__ Yv) {
  __shared__ __align__(16) ushort_t alds[2][4096];   // 8 frags * 512 shorts
  __shared__ __align__(16) ushort_t blds[2][4096];
  const int z = blockIdx.z;
  const float*    X    = (z == 0) ? Xq : (z == 1) ? Xk : Xv;
  const ushort_t* BT   = (z == 0) ? Wq : (z == 1) ? Wk : Wv;
  const float*    bias = (z == 0) ? bq : (z == 1) ? bk : bv;
  ushort_t*       Y    = (z == 0) ? Yq : (z == 1) ? Yk : Yv;
  const bool act = (z < 2);

  const int t    = threadIdx.x;
  const int m0   = blockIdx.x * 128;
  const int n0   = blockIdx.y * 128;
  const int w    = t >> 6;
  const int lane = t & 63;
  const int wm   = (w >> 1) * 64;
  const int wn   = (w & 1) * 64;
  const int lr   = lane & 15;
  const int lk   = (lane >> 4) * 8;

  // A staging map (verified r2/r4): packet p = i*256+t ->
  // fm=p>>7, lp=(p>>1)&63, half=p&1; row=fm*16+(lp&15), k=((lp>>4)&3)*8+half*4
  int row_a[4], kloc[4], ldsp[4];
  #pragma unroll
  for (int i = 0; i < 4; ++i) {
    const int p  = i * 256 + t;
    const int fm = p >> 7;
    const int lp = (p >> 1) & 63;
    row_a[i] = fm * 16 + (lp & 15);
    kloc[i]  = ((lp >> 4) & 3) * 8 + (p & 1) * 4;
    ldsp[i]  = p * 4;
  }

  // per-lane global bases for this wave's two B-frags (DMA path)
  const ushort_t* gb0 = BT + (size_t)(n0 + w * 16 + lr) * CDIM + lk;
  const ushort_t* gb1 = BT + (size_t)(n0 + (w + 4) * 16 + lr) * CDIM + lk;

  f32x4 acc[4][4];
  #pragma unroll
  for (int mi = 0; mi < 4; ++mi)
    #pragma unroll
    for (int ni = 0; ni < 4; ++ni)
      acc[mi][ni] = (f32x4){0.f, 0.f, 0.f, 0.f};

  float4 ax[4];   // A reg prefetch (loaded one iteration ahead)

  auto regloadA = [&](int kt) {
    #pragma unroll
    for (int i = 0; i < 4; ++i)
      ax[i] = *(const float4*)&X[(size_t)(m0 + row_a[i]) * CDIM + kt + kloc[i]];
  };
  auto stageA = [&](int buf) {   // cvt regs -> LDS
    #pragma unroll
    for (int i = 0; i < 4; ++i) {
      ushort4_t pa;
      pa[0] = f2bf(ax[i].x); pa[1] = f2bf(ax[i].y);
      pa[2] = f2bf(ax[i].z); pa[3] = f2bf(ax[i].w);
      *(ushort4_t*)&alds[buf][ldsp[i]] = pa;
    }
  };
  auto stageB = [&](int buf, int kt) {
    gl2lds16(gb0 + kt, &blds[buf][(w)     * 512]);
    gl2lds16(gb1 + kt, &blds[buf][(w + 4) * 512]);
  };
  auto compute = [&](int buf) {
    short8_t af[4], bfr[4];
    #pragma unroll
    for (int mi = 0; mi < 4; ++mi)
      af[mi] = *(const short8_t*)&alds[buf][((wm >> 4) + mi) * 512 + lane * 8];
    #pragma unroll
    for (int ni = 0; ni < 4; ++ni)
      bfr[ni] = *(const short8_t*)&blds[buf][((wn >> 4) + ni) * 512 + lane * 8];
    #pragma unroll
    for (int mi = 0; mi < 4; ++mi)
      #pragma unroll
      for (int ni = 0; ni < 4; ++ni)
        acc[mi][ni] = __builtin_amdgcn_mfma_f32_16x16x32_bf16(
            af[mi], bfr[ni], acc[mi][ni], 0, 0, 0);
  };

  // prologue: stage tile 0 into buf0; prefetch A regs for tile 1
  regloadA(0);
  stageA(0);
  stageB(0, 0);
  regloadA(32);

  int cur = 0;
  for (int kt = 0; kt < CDIM; kt += 32) {
    __syncthreads();   // buf[cur] staged (vm+lgkm drained); buf[cur^1] reads done
    if (kt + 32 < CDIM) {
      stageA(cur ^ 1);           // consume regs (complete: pre-barrier issue)
      stageB(cur ^ 1, kt + 32);  // DMA next B tile
      if (kt + 64 < CDIM) regloadA(kt + 64);   // issue-early for next iter
    }
    compute(cur);
    cur ^= 1;
  }

  // epilogue: C layout col=lane&15, row=(lane>>4)*4+r (verified r2)
  float bi[4];
  int coln[4];
  #pragma unroll
  for (int ni = 0; ni < 4; ++ni) {
    coln[ni] = n0 + wn + ni * 16 + lr;
    bi[ni]   = bias[coln[ni]];
  }
  #pragma unroll
  for (int mi = 0; mi < 4; ++mi) {
    #pragma unroll
    for (int r = 0; r < 4; ++r) {
      const int m = m0 + wm + mi * 16 + (lane >> 4) * 4 + r;
      #pragma unroll
      for (int ni = 0; ni < 4; ++ni) {
        float v = acc[mi][ni][r] + bi[ni];
        if (act) v = (v > 0.f) ? (v + 1.f) : expf(v);
        Y[(size_t)m * CDIM + coln[ni]] = f2bf(v);
      }
    }
  }
}

// ---------------------------------------------------------------------------
// Output projection: pure-bf16 A and B via global_load_lds, double-buffered,
// one barrier per K-step (m97 + dbuf). fp32 output to d_out.
// ---------------------------------------------------------------------------
__global__ __launch_bounds__(256)
void gemm_outp(const ushort_t* __restrict__ A, const ushort_t* __restrict__ BT,
               const float* __restrict__ bias, float* __restrict__ Y) {
  __shared__ __align__(16) ushort_t alds[2][4096];
  __shared__ __align__(16) ushort_t blds[2][4096];
  const int t    = threadIdx.x;
  const int m0   = blockIdx.x * 128;
  const int n0   = blockIdx.y * 128;
  const int w    = t >> 6;
  const int lane = t & 63;
  const int wm   = (w >> 1) * 64;
  const int wn   = (w & 1) * 64;
  const int lr   = lane & 15;
  const int lk   = (lane >> 4) * 8;

  const ushort_t* ga0 = A  + (size_t)(m0 + w * 16 + lr) * CDIM + lk;
  const ushort_t* ga1 = A  + (size_t)(m0 + (w + 4) * 16 + lr) * CDIM + lk;
  const ushort_t* gb0 = BT + (size_t)(n0 + w * 16 + lr) * CDIM + lk;
  const ushort_t* gb1 = BT + (size_t)(n0 + (w + 4) * 16 + lr) * CDIM + lk;

  f32x4 acc[4][4];
  #pragma unroll
  for (int mi = 0; mi < 4; ++mi)
    #pragma unroll
    for (int ni = 0; ni < 4; ++ni)
      acc[mi][ni] = (f32x4){0.f, 0.f, 0.f, 0.f};

  auto stage = [&](int buf, int kt) {
    gl2lds16(ga0 + kt, &alds[buf][(w)     * 512]);
    gl2lds16(ga1 + kt, &alds[buf][(w + 4) * 512]);
    gl2lds16(gb0 + kt, &blds[buf][(w)     * 512]);
    gl2lds16(gb1 + kt, &blds[buf][(w + 4) * 512]);
  };
  auto compute = [&](int buf) {
    short8_t af[4], bfr[4];
    #pragma unroll
    for (int mi = 0; mi < 4; ++mi)
      af[mi] = *(const short8_t*)&alds[buf][((wm >> 4) + mi) * 512 + lane * 8];
    #pragma unroll
    for (int ni = 0; ni < 4; ++ni)
      bfr[ni] = *(const short8_t*)&blds[buf][((wn >> 4) + ni) * 512 + lane * 8];
    #pragma unroll
    for (int mi = 0; mi < 4; ++mi)
      #pragma unroll
      for (int ni = 0; ni < 4; ++ni)
        acc[mi][ni] = __builtin_amdgcn_mfma_f32_16x16x32_bf16(
            af[mi], bfr[ni], acc[mi][ni], 0, 0, 0);
  };

  stage(0, 0);
  int cur = 0;
  for (int kt = 0; kt < CDIM; kt += 32) {
    __syncthreads();   // buf[cur] DMA drained; buf[cur^1] reads done
    if (kt + 32 < CDIM) stage(cur ^ 1, kt + 32);
    compute(cur);
    cur ^= 1;
  }

  float bi[4];
  int coln[4];
  #pragma unroll
  for (int ni = 0; ni < 4; ++ni) {
    coln[ni] = n0 + wn + ni * 16 + lr;
    bi[ni]   = bias[coln[ni]];
  }
  #pragma unroll
  for (int mi = 0; mi < 4; ++mi) {
    #pragma unroll
    for (int r = 0; r < 4; ++r) {
      const int m = m0 + wm + mi * 16 + (lane >> 4) * 4 + r;
      #pragma unroll
      for (int ni = 0; ni < 4; ++ni)
        Y[(size_t)m * CDIM + coln[ni]] = acc[mi][ni][r] + bi[ni];
    }
  }
}

// ---------------------------------------------------------------------------
// kv GEMM: per (b,h), kv[d][f] = sum_s k[s][d]*v[s][f], ksum[d] = sum_s k[s][d].
// Split-K: grid (32 bh, 16 chunks of 512 s). Reg-staged transpose into
// fragment-packed LDS (A = k^T, B = v); ksum via ones-B-fragment MFMA.
// ---------------------------------------------------------------------------
__global__ __launch_bounds__(256)
void gemm_kv(const ushort_t* __restrict__ Kb, const ushort_t* __restrict__ Vb,
             float* __restrict__ kvpart, float* __restrict__ ksumpart) {
  __shared__ __align__(16) ushort_t klds[8192];
  __shared__ __align__(16) ushort_t vlds[8192];
  const int bh    = blockIdx.x;
  const int chunk = blockIdx.y;
  const int b = bh >> 3, h = bh & 7;
  const int t = threadIdx.x;
  const int w = t >> 6;
  const int lane = t & 63;

  f32x4 acc[4];
  #pragma unroll
  for (int fg = 0; fg < 4; ++fg) acc[fg] = (f32x4){0.f, 0.f, 0.f, 0.f};
  f32x4 accs = (f32x4){0.f, 0.f, 0.f, 0.f};

  short8_t ones;
  #pragma unroll
  for (int i = 0; i < 8; ++i) ones[i] = (short)0x3F80;

  for (int round = 0; round < 4; ++round) {
    const int sbase = chunk * 512 + round * 128;
    __syncthreads();
    #pragma unroll
    for (int i = 0; i < 4; ++i) {
      const int idx  = i * 256 + t;
      const int sl   = idx >> 3;
      const int d8   = idx & 7;
      const size_t src = (size_t)((sbase + sl) * BATCH + b) * CDIM + h * DDIM + d8 * 8;
      const ushort8_t kp = *(const ushort8_t*)&Kb[src];
      const ushort8_t vp = *(const ushort8_t*)&Vb[src];
      const int sb  = sl >> 5;
      const int j   = sl & 7;
      const int lp0 = (d8 & 1) * 8 + ((sl >> 3) & 3) * 16;
      const int dg  = d8 >> 1;
      const int kbase = ((sb * 4 + dg) * 64 + lp0) * 8 + j;
      #pragma unroll
      for (int e = 0; e < 8; ++e) {
        klds[kbase + e * 8] = kp[e];
        vlds[kbase + e * 8] = vp[e];
      }
    }
    __syncthreads();
    #pragma unroll
    for (int sb = 0; sb < 4; ++sb) {
      const short8_t af = *(const short8_t*)&klds[((sb * 4 + w) * 64 + lane) * 8];
      accs = __builtin_amdgcn_mfma_f32_16x16x32_bf16(af, ones, accs, 0, 0, 0);
      #pragma unroll
      for (int fg = 0; fg < 4; ++fg) {
        const short8_t bf = *(const short8_t*)&vlds[((sb * 4 + fg) * 64 + lane) * 8];
        acc[fg] = __builtin_amdgcn_mfma_f32_16x16x32_bf16(af, bf, acc[fg], 0, 0, 0);
      }
    }
  }

  const size_t obase = ((size_t)bh * 16 + chunk) * 64;
  #pragma unroll
  for (int fg = 0; fg < 4; ++fg)
    #pragma unroll
    for (int r = 0; r < 4; ++r) {
      const int d = w * 16 + (lane >> 4) * 4 + r;
      kvpart[(obase + d) * 64 + fg * 16 + (lane & 15)] = acc[fg][r];
    }
  if ((lane & 15) == 0) {
    #pragma unroll
    for (int r = 0; r < 4; ++r)
      ksumpart[obase + w * 16 + (lane >> 4) * 4 + r] = accs[r];
  }
}

// ---------------------------------------------------------------------------
__global__ __launch_bounds__(256)
void kv_finish(const float* __restrict__ kvpart, const float* __restrict__ ksumpart,
               ushort_t* __restrict__ kvT) {
  const int bh = blockIdx.x;
  const int t  = threadIdx.x;
  for (int idx = t; idx < 4096; idx += 256) {
    const int d = idx >> 6, f = idx & 63;
    float s = 0.f;
    for (int c = 0; c < 16; ++c)
      s += kvpart[(((size_t)bh * 16 + c) * 64 + d) * 64 + f];
    kvT[((size_t)bh * 80 + f) * 64 + d] = f2bf(s);
  }
  if (t < 64) {
    float s = 0.f;
    for (int c = 0; c < 16; ++c)
      s += ksumpart[((size_t)bh * 16 + c) * 64 + t];
    kvT[((size_t)bh * 80 + 64) * 64 + t] = f2bf(s);
  }
  for (int i = t; i < 15 * 64; i += 256)
    kvT[((size_t)bh * 80 + 65) * 64 + i] = 0;
}

// ---------------------------------------------------------------------------
// qkv GEMM: y = (q @ kv) / (q . ksum + eps); B = kvT_pad [80][64], col 64 = denom.
// ---------------------------------------------------------------------------
__global__ __launch_bounds__(256)
void gemm_qkv(ushort_t* __restrict__ Qb, const ushort_t* __restrict__ kvT) {
  __shared__ __align__(16) ushort_t alds[8192];
  __shared__ __align__(16) ushort_t blds[5120];
  const int bh    = blockIdx.x;
  const int chunk = blockIdx.y;
  const int b = bh >> 3, h = bh & 7;
  const int t = threadIdx.x;
  const int w = t >> 6;
  const int lane = t & 63;
  const int lr = lane & 15;
  const int lk = (lane >> 4) * 8;

  #pragma unroll
  for (int i = 0; i < 4; ++i) {
    const int fidx = w * 4 + i;
    const int ks = fidx >> 3, fm = fidx & 7;
    const ushort_t* src = Qb +
        (size_t)((chunk * 128 + fm * 16 + lr) * BATCH + b) * CDIM +
        h * DDIM + ks * 32 + lk;
    gl2lds16(src, &alds[fidx * 512]);
  }
  for (int idx = w; idx < 10; idx += 4) {
    const int ks = idx / 5, fg = idx % 5;
    const ushort_t* src = kvT + (size_t)(bh * 80 + fg * 16 + lr) * 64 + ks * 32 + lk;
    gl2lds16(src, &blds[idx * 512]);
  }
  __syncthreads();

  f32x4 acc[2][5];
  #pragma unroll
  for (int mi = 0; mi < 2; ++mi)
    #pragma unroll
    for (int fg = 0; fg < 5; ++fg)
      acc[mi][fg] = (f32x4){0.f, 0.f, 0.f, 0.f};

  #pragma unroll
  for (int ks = 0; ks < 2; ++ks) {
    short8_t af[2], bf[5];
    #pragma unroll
    for (int mi = 0; mi < 2; ++mi)
      af[mi] = *(const short8_t*)&alds[(ks * 8 + w * 2 + mi) * 512 + lane * 8];
    #pragma unroll
    for (int fg = 0; fg < 5; ++fg)
      bf[fg] = *(const short8_t*)&blds[(ks * 5 + fg) * 512 + lane * 8];
    #pragma unroll
    for (int mi = 0; mi < 2; ++mi)
      #pragma unroll
      for (int fg = 0; fg < 5; ++fg)
        acc[mi][fg] = __builtin_amdgcn_mfma_f32_16x16x32_bf16(
            af[mi], bf[fg], acc[mi][fg], 0, 0, 0);
  }

  #pragma unroll
  for (int mi = 0; mi < 2; ++mi) {
    #pragma unroll
    for (int r = 0; r < 4; ++r) {
      const float dv  = __shfl(acc[mi][4][r], lane & 48);
      const float inv = 1.f / (dv + EPS_F);
      const int s = chunk * 128 + w * 32 + mi * 16 + (lane >> 4) * 4 + r;
      const size_t rowb = (size_t)(s * BATCH + b) * CDIM + h * DDIM;
      #pragma unroll
      for (int fg = 0; fg < 4; ++fg)
        Qb[rowb + fg * 16 + lr] = f2bf(acc[mi][fg][r] * inv);
    }
  }
}

// ---------------------------------------------------------------------------
extern "C" void kernel_launch(void* const* d_in, const int* in_sizes, int n_in,
                              void* d_out, int out_size, void* d_ws, size_t ws_size,
                              hipStream_t stream) {
  const float* q_in = (const float*)d_in[0];
  const float* k_in = (const float*)d_in[1];
  const float* v_in = (const float*)d_in[2];
  const float* Wq   = (const float*)d_in[3];
  const float* bq   = (const float*)d_in[4];
  const float* Wk   = (const float*)d_in[5];
  const float* bk   = (const float*)d_in[6];
  const float* Wv   = (const float*)d_in[7];
  const float* bv   = (const float*)d_in[8];
  const float* Wp   = (const float*)d_in[9];
  const float* bp   = (const float*)d_in[10];
  float* out = (float*)d_out;

  const size_t NTOK = (size_t)MROWS * CDIM;      // 16,777,216 elems
  const size_t NW   = (size_t)CDIM * CDIM;       // 262,144
  ushort_t* Wq_bf  = (ushort_t*)d_ws;
  ushort_t* Wk_bf  = Wq_bf + NW;
  ushort_t* Wv_bf  = Wk_bf + NW;
  ushort_t* Wp_bf  = Wv_bf + NW;
  ushort_t* qbuf   = Wp_bf + NW;
  ushort_t* kbuf   = qbuf + NTOK;
  ushort_t* vbuf   = kbuf + NTOK;
  ushort_t* kvT    = vbuf + NTOK;                           // 32*80*64
  float* kvpart    = (float*)(kvT + (size_t)32 * 80 * 64);  // 512*64*64
  float* ksumpart  = kvpart + (size_t)512 * 64 * 64;        // 512*64

  const dim3 blk(256);

  // 1) Weights fp32 -> bf16
  cvtW_kernel<<<dim3(128, 4), blk, 0, stream>>>(Wq, Wk, Wv, Wp,
                                                Wq_bf, Wk_bf, Wv_bf, Wp_bf);

  // 2) Q/K/V projections in ONE launch (dbuf, 1 barrier/K-step, T14 A-prefetch)
  gemm_proj3<<<dim3(MROWS / 128, CDIM / 128, 3), blk, 0, stream>>>(
      q_in, k_in, v_in, Wq_bf, Wk_bf, Wv_bf, bq, bk, bv, qbuf, kbuf, vbuf);

  // 3) kv = sum_s k^T v (+ ksum via ones-MFMA), split-K then finish
  gemm_kv<<<dim3(32, 16), blk, 0, stream>>>(kbuf, vbuf, kvpart, ksumpart);
  kv_finish<<<dim3(32), blk, 0, stream>>>(kvpart, ksumpart, kvT);

  // 4) y = (q @ kv) / (q . ksum + eps), bf16 in place over q buffer
  gemm_qkv<<<dim3(32, 64), blk, 0, stream>>>(qbuf, kvT);

  // 5) Output projection (dbuf DMA both operands) -> fp32 d_out
  gemm_outp<<<dim3(MROWS / 128, CDIM / 128), blk, 0, stream>>>(
      qbuf, Wp_bf, bp, out);
}

// Round 8
// 239.499 us; speedup vs baseline: 1.8136x; 1.1004x over previous
//
#include <hip/hip_runtime.h>
#include <hip/hip_bf16.h>
#include <math.h>

// Problem constants: S=8192, B=4, C=512, H=8, D=64
#define S_LEN 8192
#define BATCH 4
#define CDIM  512
#define HEADS 8
#define DDIM  64
#define MROWS (S_LEN * BATCH)   // 32768 rows; row m = s*BATCH + b; layout [S,B,C]
#define EPS_F 1e-6f

typedef __attribute__((ext_vector_type(8))) short     short8_t;
typedef __attribute__((ext_vector_type(4))) float     f32x4;
typedef unsigned short ushort_t;
typedef __attribute__((ext_vector_type(4))) unsigned short ushort4_t;
typedef __attribute__((ext_vector_type(8))) unsigned short ushort8_t;

static __device__ __forceinline__ ushort_t f2bf(float f) {
  __hip_bfloat16 h = __float2bfloat16(f);   // RNE
  return *(ushort_t*)&h;
}

// Async global->LDS, 16B per lane. LDS dest = wave-uniform base + lane*16.
static __device__ __forceinline__ void gl2lds16(const ushort_t* g, ushort_t* l) {
  __builtin_amdgcn_global_load_lds((const __attribute__((address_space(1))) void*)g,
                                   (__attribute__((address_space(3))) void*)l,
                                   16, 0, 0);
}

// ---------------------------------------------------------------------------
// Weights fp32 -> bf16 (4 MB total, ~3 us)
// ---------------------------------------------------------------------------
__global__ __launch_bounds__(256)
void cvtW_kernel(const float* __restrict__ a, const float* __restrict__ b,
                 const float* __restrict__ c, const float* __restrict__ d,
                 ushort_t* __restrict__ oa, ushort_t* __restrict__ ob,
                 ushort_t* __restrict__ oc, ushort_t* __restrict__ od) {
  const float* src = (blockIdx.y == 0) ? a : (blockIdx.y == 1) ? b :
                     (blockIdx.y == 2) ? c : d;
  ushort_t* dst    = (blockIdx.y == 0) ? oa : (blockIdx.y == 1) ? ob :
                     (blockIdx.y == 2) ? oc : od;
  const size_t i = ((size_t)blockIdx.x * 256 + threadIdx.x) * 8;
  const float4 x = *(const float4*)&src[i];
  const float4 y = *(const float4*)&src[i + 4];
  ushort8_t p;
  p[0] = f2bf(x.x); p[1] = f2bf(x.y); p[2] = f2bf(x.z); p[3] = f2bf(x.w);
  p[4] = f2bf(y.x); p[5] = f2bf(y.y); p[6] = f2bf(y.z); p[7] = f2bf(y.w);
  *(ushort8_t*)&dst[i] = p;
}

// ---------------------------------------------------------------------------
// A-register-resident row-panel GEMM:
//   Y[m][n] = act( sum_k A[m][k]*BT[n][k] + bias[n] ),  K = N = 512.
// Block = 64 m-rows, 256 thr = 4 waves; wave w owns rows m0+w*16..+15.
// A: the wave's ENTIRE K=512 panel lives in registers (16 frags x 8 bf16 =
//    64 VGPR), loaded once (fp32->cvt in-reg if AF32) -- A read from HBM
//    exactly once, never re-staged, never behind a barrier.
// B: L2-resident weights staged per (n-tile, BK=64 step) via global_load_lds
//    into fragment-packed LDS (frag = 64 lanes x 16B, conflict-free
//    ds_read_b128), double-buffered, ONE barrier per step.
// n-loop: 4 tiles of 128 cols; acc = 8 f32x4; epilogue per tile.
// ---------------------------------------------------------------------------
template<int AF32, int OUTF32>
static __device__ __forceinline__
void rowpanel_body(const void* __restrict__ Av, const ushort_t* __restrict__ BT,
                   const float* __restrict__ bias, void* __restrict__ Yv,
                   const bool act, const int m0, ushort_t (*blds)[8192]) {
  const int t    = threadIdx.x;
  const int w    = t >> 6;
  const int lane = t & 63;
  const int lr   = lane & 15;          // row/col-in-frag
  const int lk   = (lane >> 4) * 8;    // k-offset-in-frag
  const int arow = m0 + w * 16 + lr;

  const float*    Af = (const float*)Av;
  const ushort_t* Ah = (const ushort_t*)Av;

  // ---- A panel -> registers (once) ----
  short8_t afr[16];
  #pragma unroll
  for (int kf = 0; kf < 16; ++kf) {
    if (AF32) {
      const float4 x0 = *(const float4*)&Af[(size_t)arow * CDIM + kf * 32 + lk];
      const float4 x1 = *(const float4*)&Af[(size_t)arow * CDIM + kf * 32 + lk + 4];
      short8_t v;
      v[0] = (short)f2bf(x0.x); v[1] = (short)f2bf(x0.y);
      v[2] = (short)f2bf(x0.z); v[3] = (short)f2bf(x0.w);
      v[4] = (short)f2bf(x1.x); v[5] = (short)f2bf(x1.y);
      v[6] = (short)f2bf(x1.z); v[7] = (short)f2bf(x1.w);
      afr[kf] = v;
    } else {
      afr[kf] = *(const short8_t*)&Ah[(size_t)arow * CDIM + kf * 32 + lk];
    }
  }

  for (int nt = 0; nt < 4; ++nt) {
    const int n0 = nt * 128;
    f32x4 acc[8];
    #pragma unroll
    for (int nf = 0; nf < 8; ++nf) acc[nf] = (f32x4){0.f, 0.f, 0.f, 0.f};

    // stage one BK=64 x 128n B tile (16 frags); wave stages frags w*4..w*4+3
    auto stageB = [&](int buf, int ks) {
      #pragma unroll
      for (int i = 0; i < 4; ++i) {
        const int fid = w * 4 + i;           // 0..15
        const int k2 = fid >> 3, nf = fid & 7;
        gl2lds16(BT + (size_t)(n0 + nf * 16 + lr) * CDIM + ks * 64 + k2 * 32 + lk,
                 &blds[buf][fid * 512]);
      }
    };

    stageB(0, 0);
    int cur = 0;
    #pragma unroll
    for (int ks = 0; ks < 8; ++ks) {
      __syncthreads();                 // buf[cur] DMA drained; buf[cur^1] reads done
      if (ks < 7) stageB(cur ^ 1, ks + 1);
      #pragma unroll
      for (int k2 = 0; k2 < 2; ++k2) {
        short8_t bfr[8];
        #pragma unroll
        for (int nf = 0; nf < 8; ++nf)
          bfr[nf] = *(const short8_t*)&blds[cur][(k2 * 8 + nf) * 512 + lane * 8];
        #pragma unroll
        for (int nf = 0; nf < 8; ++nf)
          acc[nf] = __builtin_amdgcn_mfma_f32_16x16x32_bf16(
              afr[ks * 2 + k2], bfr[nf], acc[nf], 0, 0, 0);
      }
      cur ^= 1;
    }

    // ---- epilogue: C layout col=lane&15, row=(lane>>4)*4+r (verified r2) ----
    float* Yf = (float*)Yv;
    ushort_t* Yh = (ushort_t*)Yv;
    #pragma unroll
    for (int nf = 0; nf < 8; ++nf) {
      const int col = n0 + nf * 16 + lr;
      const float bi = bias[col];
      #pragma unroll
      for (int r = 0; r < 4; ++r) {
        const int m = m0 + w * 16 + (lane >> 4) * 4 + r;
        float vv = acc[nf][r] + bi;
        if (act) vv = (vv > 0.f) ? (vv + 1.f) : expf(vv);
        if (OUTF32) Yf[(size_t)m * CDIM + col] = vv;
        else        Yh[(size_t)m * CDIM + col] = f2bf(vv);
      }
    }
  }
}

// Q/K/V projections fused in one launch: blockIdx.y = z in {q,k,v}
__global__ __launch_bounds__(256)
void proj3_rowpanel(const float* __restrict__ Xq, const float* __restrict__ Xk,
                    const float* __restrict__ Xv,
                    const ushort_t* __restrict__ Wq, const ushort_t* __restrict__ Wk,
                    const ushort_t* __restrict__ Wv,
                    const float* __restrict__ bq, const float* __restrict__ bk,
                    const float* __restrict__ bv,
                    ushort_t* __restrict__ Yq, ushort_t* __restrict__ Yk,
                    ushort_t* __restrict__ Yv) {
  __shared__ __align__(16) ushort_t blds[2][8192];
  const int z = blockIdx.y;
  const float*    X    = (z == 0) ? Xq : (z == 1) ? Xk : Xv;
  const ushort_t* BT   = (z == 0) ? Wq : (z == 1) ? Wk : Wv;
  const float*    bias = (z == 0) ? bq : (z == 1) ? bk : bv;
  ushort_t*       Y    = (z == 0) ? Yq : (z == 1) ? Yk : Yv;
  rowpanel_body<1, 0>(X, BT, bias, Y, z < 2, blockIdx.x * 64, blds);
}

// Output projection: bf16 A, fp32 out
__global__ __launch_bounds__(256)
void outp_rowpanel(const ushort_t* __restrict__ A, const ushort_t* __restrict__ BT,
                   const float* __restrict__ bias, float* __restrict__ Y) {
  __shared__ __align__(16) ushort_t blds[2][8192];
  rowpanel_body<0, 1>(A, BT, bias, Y, false, blockIdx.x * 64, blds);
}

// ---------------------------------------------------------------------------
// kv GEMM: per (b,h), kv[d][f] = sum_s k[s][d]*v[s][f], ksum[d] = sum_s k[s][d].
// Split-K: grid (32 bh, 16 chunks of 512 s). Reg-staged transpose into
// fragment-packed LDS (A = k^T, B = v); ksum via ones-B-fragment MFMA.
// ---------------------------------------------------------------------------
__global__ __launch_bounds__(256)
void gemm_kv(const ushort_t* __restrict__ Kb, const ushort_t* __restrict__ Vb,
             float* __restrict__ kvpart, float* __restrict__ ksumpart) {
  __shared__ __align__(16) ushort_t klds[8192];
  __shared__ __align__(16) ushort_t vlds[8192];
  const int bh    = blockIdx.x;
  const int chunk = blockIdx.y;
  const int b = bh >> 3, h = bh & 7;
  const int t = threadIdx.x;
  const int w = t >> 6;
  const int lane = t & 63;

  f32x4 acc[4];
  #pragma unroll
  for (int fg = 0; fg < 4; ++fg) acc[fg] = (f32x4){0.f, 0.f, 0.f, 0.f};
  f32x4 accs = (f32x4){0.f, 0.f, 0.f, 0.f};

  short8_t ones;
  #pragma unroll
  for (int i = 0; i < 8; ++i) ones[i] = (short)0x3F80;

  for (int round = 0; round < 4; ++round) {
    const int sbase = chunk * 512 + round * 128;
    __syncthreads();
    #pragma unroll
    for (int i = 0; i < 4; ++i) {
      const int idx  = i * 256 + t;
      const int sl   = idx >> 3;
      const int d8   = idx & 7;
      const size_t src = (size_t)((sbase + sl) * BATCH + b) * CDIM + h * DDIM + d8 * 8;
      const ushort8_t kp = *(const ushort8_t*)&Kb[src];
      const ushort8_t vp = *(const ushort8_t*)&Vb[src];
      const int sb  = sl >> 5;
      const int j   = sl & 7;
      const int lp0 = (d8 & 1) * 8 + ((sl >> 3) & 3) * 16;
      const int dg  = d8 >> 1;
      const int kbase = ((sb * 4 + dg) * 64 + lp0) * 8 + j;
      #pragma unroll
      for (int e = 0; e < 8; ++e) {
        klds[kbase + e * 8] = kp[e];
        vlds[kbase + e * 8] = vp[e];
      }
    }
    __syncthreads();
    #pragma unroll
    for (int sb = 0; sb < 4; ++sb) {
      const short8_t af = *(const short8_t*)&klds[((sb * 4 + w) * 64 + lane) * 8];
      accs = __builtin_amdgcn_mfma_f32_16x16x32_bf16(af, ones, accs, 0, 0, 0);
      #pragma unroll
      for (int fg = 0; fg < 4; ++fg) {
        const short8_t bf = *(const short8_t*)&vlds[((sb * 4 + fg) * 64 + lane) * 8];
        acc[fg] = __builtin_amdgcn_mfma_f32_16x16x32_bf16(af, bf, acc[fg], 0, 0, 0);
      }
    }
  }

  const size_t obase = ((size_t)bh * 16 + chunk) * 64;
  #pragma unroll
  for (int fg = 0; fg < 4; ++fg)
    #pragma unroll
    for (int r = 0; r < 4; ++r) {
      const int d = w * 16 + (lane >> 4) * 4 + r;
      kvpart[(obase + d) * 64 + fg * 16 + (lane & 15)] = acc[fg][r];
    }
  if ((lane & 15) == 0) {
    #pragma unroll
    for (int r = 0; r < 4; ++r)
      ksumpart[obase + w * 16 + (lane >> 4) * 4 + r] = accs[r];
  }
}

// ---------------------------------------------------------------------------
__global__ __launch_bounds__(256)
void kv_finish(const float* __restrict__ kvpart, const float* __restrict__ ksumpart,
               ushort_t* __restrict__ kvT) {
  const int bh = blockIdx.x;
  const int t  = threadIdx.x;
  for (int idx = t; idx < 4096; idx += 256) {
    const int d = idx >> 6, f = idx & 63;
    float s = 0.f;
    for (int c = 0; c < 16; ++c)
      s += kvpart[(((size_t)bh * 16 + c) * 64 + d) * 64 + f];
    kvT[((size_t)bh * 80 + f) * 64 + d] = f2bf(s);
  }
  if (t < 64) {
    float s = 0.f;
    for (int c = 0; c < 16; ++c)
      s += ksumpart[((size_t)bh * 16 + c) * 64 + t];
    kvT[((size_t)bh * 80 + 64) * 64 + t] = f2bf(s);
  }
  for (int i = t; i < 15 * 64; i += 256)
    kvT[((size_t)bh * 80 + 65) * 64 + i] = 0;
}

// ---------------------------------------------------------------------------
// qkv GEMM: y = (q @ kv) / (q . ksum + eps); B = kvT_pad [80][64], col 64 = denom.
// ---------------------------------------------------------------------------
__global__ __launch_bounds__(256)
void gemm_qkv(ushort_t* __restrict__ Qb, const ushort_t* __restrict__ kvT) {
  __shared__ __align__(16) ushort_t alds[8192];
  __shared__ __align__(16) ushort_t blds[5120];
  const int bh    = blockIdx.x;
  const int chunk = blockIdx.y;
  const int b = bh >> 3, h = bh & 7;
  const int t = threadIdx.x;
  const int w = t >> 6;
  const int lane = t & 63;
  const int lr = lane & 15;
  const int lk = (lane >> 4) * 8;

  #pragma unroll
  for (int i = 0; i < 4; ++i) {
    const int fidx = w * 4 + i;
    const int ks = fidx >> 3, fm = fidx & 7;
    const ushort_t* src = Qb +
        (size_t)((chunk * 128 + fm * 16 + lr) * BATCH + b) * CDIM +
        h * DDIM + ks * 32 + lk;
    gl2lds16(src, &alds[fidx * 512]);
  }
  for (int idx = w; idx < 10; idx += 4) {
    const int ks = idx / 5, fg = idx % 5;
    const ushort_t* src = kvT + (size_t)(bh * 80 + fg * 16 + lr) * 64 + ks * 32 + lk;
    gl2lds16(src, &blds[idx * 512]);
  }
  __syncthreads();

  f32x4 acc[2][5];
  #pragma unroll
  for (int mi = 0; mi < 2; ++mi)
    #pragma unroll
    for (int fg = 0; fg < 5; ++fg)
      acc[mi][fg] = (f32x4){0.f, 0.f, 0.f, 0.f};

  #pragma unroll
  for (int ks = 0; ks < 2; ++ks) {
    short8_t af[2], bf[5];
    #pragma unroll
    for (int mi = 0; mi < 2; ++mi)
      af[mi] = *(const short8_t*)&alds[(ks * 8 + w * 2 + mi) * 512 + lane * 8];
    #pragma unroll
    for (int fg = 0; fg < 5; ++fg)
      bf[fg] = *(const short8_t*)&blds[(ks * 5 + fg) * 512 + lane * 8];
    #pragma unroll
    for (int mi = 0; mi < 2; ++mi)
      #pragma unroll
      for (int fg = 0; fg < 5; ++fg)
        acc[mi][fg] = __builtin_amdgcn_mfma_f32_16x16x32_bf16(
            af[mi], bf[fg], acc[mi][fg], 0, 0, 0);
  }

  #pragma unroll
  for (int mi = 0; mi < 2; ++mi) {
    #pragma unroll
    for (int r = 0; r < 4; ++r) {
      const float dv  = __shfl(acc[mi][4][r], lane & 48);
      const float inv = 1.f / (dv + EPS_F);
      const int s = chunk * 128 + w * 32 + mi * 16 + (lane >> 4) * 4 + r;
      const size_t rowb = (size_t)(s * BATCH + b) * CDIM + h * DDIM;
      #pragma unroll
      for (int fg = 0; fg < 4; ++fg)
        Qb[rowb + fg * 16 + lr] = f2bf(acc[mi][fg][r] * inv);
    }
  }
}

// ---------------------------------------------------------------------------
extern "C" void kernel_launch(void* const* d_in, const int* in_sizes, int n_in,
                              void* d_out, int out_size, void* d_ws, size_t ws_size,
                              hipStream_t stream) {
  const float* q_in = (const float*)d_in[0];
  const float* k_in = (const float*)d_in[1];
  const float* v_in = (const float*)d_in[2];
  const float* Wq   = (const float*)d_in[3];
  const float* bq   = (const float*)d_in[4];
  const float* Wk   = (const float*)d_in[5];
  const float* bk   = (const float*)d_in[6];
  const float* Wv   = (const float*)d_in[7];
  const float* bv   = (const float*)d_in[8];
  const float* Wp   = (const float*)d_in[9];
  const float* bp   = (const float*)d_in[10];
  float* out = (float*)d_out;

  const size_t NTOK = (size_t)MROWS * CDIM;      // 16,777,216 elems
  const size_t NW   = (size_t)CDIM * CDIM;       // 262,144
  ushort_t* Wq_bf  = (ushort_t*)d_ws;
  ushort_t* Wk_bf  = Wq_bf + NW;
  ushort_t* Wv_bf  = Wk_bf + NW;
  ushort_t* Wp_bf  = Wv_bf + NW;
  ushort_t* qbuf   = Wp_bf + NW;
  ushort_t* kbuf   = qbuf + NTOK;
  ushort_t* vbuf   = kbuf + NTOK;
  ushort_t* kvT    = vbuf + NTOK;                           // 32*80*64
  float* kvpart    = (float*)(kvT + (size_t)32 * 80 * 64);  // 512*64*64
  float* ksumpart  = kvpart + (size_t)512 * 64 * 64;        // 512*64

  const dim3 blk(256);

  // 1) Weights fp32 -> bf16
  cvtW_kernel<<<dim3(128, 4), blk, 0, stream>>>(Wq, Wk, Wv, Wp,
                                                Wq_bf, Wk_bf, Wv_bf, Wp_bf);

  // 2) Q/K/V projections: A-register-resident row-panel (A read once)
  proj3_rowpanel<<<dim3(MROWS / 64, 3), blk, 0, stream>>>(
      q_in, k_in, v_in, Wq_bf, Wk_bf, Wv_bf, bq, bk, bv, qbuf, kbuf, vbuf);

  // 3) kv = sum_s k^T v (+ ksum via ones-MFMA), split-K then finish
  gemm_kv<<<dim3(32, 16), blk, 0, stream>>>(kbuf, vbuf, kvpart, ksumpart);
  kv_finish<<<dim3(32), blk, 0, stream>>>(kvpart, ksumpart, kvT);

  // 4) y = (q @ kv) / (q . ksum + eps), bf16 in place over q buffer
  gemm_qkv<<<dim3(32, 64), blk, 0, stream>>>(qbuf, kvT);

  // 5) Output projection: row-panel, bf16 A -> fp32 d_out
  outp_rowpanel<<<dim3(MROWS / 64), blk, 0, stream>>>(qbuf, Wp_bf, bp, out);
}

// Round 9
// 234.447 us; speedup vs baseline: 1.8527x; 1.0215x over previous
//
#include <hip/hip_runtime.h>
#include <hip/hip_bf16.h>
#include <math.h>

// Problem constants: S=8192, B=4, C=512, H=8, D=64
#define S_LEN 8192
#define BATCH 4
#define CDIM  512
#define HEADS 8
#define DDIM  64
#define MROWS (S_LEN * BATCH)   // 32768 rows; row m = s*BATCH + b; layout [S,B,C]
#define EPS_F 1e-6f

typedef __attribute__((ext_vector_type(8))) short     short8_t;
typedef __attribute__((ext_vector_type(4))) float     f32x4;
typedef unsigned short ushort_t;
typedef __attribute__((ext_vector_type(4))) unsigned short ushort4_t;
typedef __attribute__((ext_vector_type(8))) unsigned short ushort8_t;

static __device__ __forceinline__ ushort_t f2bf(float f) {
  __hip_bfloat16 h = __float2bfloat16(f);   // RNE
  return *(ushort_t*)&h;
}

// Async global->LDS, 16B per lane. LDS dest = wave-uniform base + lane*16.
static __device__ __forceinline__ void gl2lds16(const ushort_t* g, ushort_t* l) {
  __builtin_amdgcn_global_load_lds((const __attribute__((address_space(1))) void*)g,
                                   (__attribute__((address_space(3))) void*)l,
                                   16, 0, 0);
}

// ---------------------------------------------------------------------------
// Weights fp32 -> bf16, packed FRAGMENT-MAJOR:
//   frag (nfg 0..31, kf 0..15): 64 lanes x 8 shorts contiguous (1 KB).
//   lane = ((k>>3)&3)*16 + (n&15); elem j = k&7.
// Makes GEMM B-loads 1 KB contiguous per fragment (perfectly coalesced).
// ---------------------------------------------------------------------------
__global__ __launch_bounds__(256)
void cvtW_pack(const float* __restrict__ a, const float* __restrict__ b,
               const float* __restrict__ c, const float* __restrict__ d,
               ushort_t* __restrict__ oa, ushort_t* __restrict__ ob,
               ushort_t* __restrict__ oc, ushort_t* __restrict__ od) {
  const float* src = (blockIdx.y == 0) ? a : (blockIdx.y == 1) ? b :
                     (blockIdx.y == 2) ? c : d;
  ushort_t* dst    = (blockIdx.y == 0) ? oa : (blockIdx.y == 1) ? ob :
                     (blockIdx.y == 2) ? oc : od;
  const size_t i = ((size_t)blockIdx.x * 256 + threadIdx.x) * 8;
  const int n  = (int)(i >> 9);        // W row (output col)
  const int k0 = (int)(i & 511);       // 8 consecutive k
  const float4 x = *(const float4*)&src[i];
  const float4 y = *(const float4*)&src[i + 4];
  ushort8_t p;
  p[0] = f2bf(x.x); p[1] = f2bf(x.y); p[2] = f2bf(x.z); p[3] = f2bf(x.w);
  p[4] = f2bf(y.x); p[5] = f2bf(y.y); p[6] = f2bf(y.z); p[7] = f2bf(y.w);
  const int kf   = k0 >> 5;
  const int lane = ((k0 >> 3) & 3) * 16 + (n & 15);
  const int nfg  = n >> 4;
  *(ushort8_t*)&dst[(((size_t)nfg * 16 + kf) * 64 + lane) * 8] = p;
}

// ---------------------------------------------------------------------------
// Barrier-free GEMM main body (A in LDS frag-packed, staged ONCE):
//   Y[m][n] = act( sum_k A[m][k]*W[n][k] + bias[n] ),  K = N = 512.
// Block = 64 m-rows, 256 thr = 4 waves; wave w owns n-cols w*128..+127.
// A: 64x512 bf16 frag-packed in LDS (64 frags x 1KB), staged once + 1 barrier.
// B: frag-packed weights (Wpk) read global->reg, 1KB/frag coalesced, L2-hot,
//    1-kf prefetch depth. Main loop: ds_read + global-reg + 512 MFMA, ZERO
//    barriers -> nothing drains, compiler schedules freely.
// acc = 4 mf x 8 nf f32x4 (128 VGPR).
// ---------------------------------------------------------------------------
template<int OUTF32>
static __device__ __forceinline__
void nobar_compute(const ushort_t* __restrict__ alds,
                   const ushort_t* __restrict__ Wpk,
                   const float* __restrict__ bias, void* __restrict__ Yv,
                   const bool act, const int m0) {
  const int t    = threadIdx.x;
  const int w    = t >> 6;       // wave = n-quarter
  const int lane = t & 63;

  f32x4 acc[4][8];
  #pragma unroll
  for (int mi = 0; mi < 4; ++mi)
    #pragma unroll
    for (int nf = 0; nf < 8; ++nf)
      acc[mi][nf] = (f32x4){0.f, 0.f, 0.f, 0.f};

  short8_t a_[4], b0[8], b1[8];

  auto LB = [&](int kf, short8_t (&bb)[8]) {
    #pragma unroll
    for (int nf = 0; nf < 8; ++nf)
      bb[nf] = *(const short8_t*)&Wpk[(((size_t)(w * 8 + nf) * 16 + kf) * 64 + lane) * 8];
  };
  auto LA = [&](int kf) {
    #pragma unroll
    for (int mi = 0; mi < 4; ++mi)
      a_[mi] = *(const short8_t*)&alds[((kf * 4 + mi) * 64 + lane) * 8];
  };
  auto MF = [&](short8_t (&bb)[8]) {
    #pragma unroll
    for (int mi = 0; mi < 4; ++mi)
      #pragma unroll
      for (int nf = 0; nf < 8; ++nf)
        acc[mi][nf] = __builtin_amdgcn_mfma_f32_16x16x32_bf16(
            a_[mi], bb[nf], acc[mi][nf], 0, 0, 0);
  };

  LB(0, b0);
  #pragma unroll
  for (int kk = 0; kk < 8; ++kk) {
    LB(kk * 2 + 1, b1);
    LA(kk * 2);
    MF(b0);
    if (kk < 7) LB(kk * 2 + 2, b0);
    LA(kk * 2 + 1);
    MF(b1);
  }

  // epilogue: C layout col=lane&15, row=(lane>>4)*4+r (verified r2)
  float* Yf = (float*)Yv;
  ushort_t* Yh = (ushort_t*)Yv;
  #pragma unroll
  for (int nf = 0; nf < 8; ++nf) {
    const int col = w * 128 + nf * 16 + (lane & 15);
    const float bi = bias[col];
    #pragma unroll
    for (int mi = 0; mi < 4; ++mi) {
      #pragma unroll
      for (int r = 0; r < 4; ++r) {
        const int m = m0 + mi * 16 + (lane >> 4) * 4 + r;
        float vv = acc[mi][nf][r] + bi;
        if (act) vv = (vv > 0.f) ? (vv + 1.f) : expf(vv);
        if (OUTF32) Yf[(size_t)m * CDIM + col] = vv;
        else        Yh[(size_t)m * CDIM + col] = f2bf(vv);
      }
    }
  }
}

// Q/K/V projections (fp32 A, cvt while staging), blockIdx.y = z in {q,k,v}
__global__ __launch_bounds__(256)
void proj3_nobar(const float* __restrict__ Xq, const float* __restrict__ Xk,
                 const float* __restrict__ Xv,
                 const ushort_t* __restrict__ Wqp, const ushort_t* __restrict__ Wkp,
                 const ushort_t* __restrict__ Wvp,
                 const float* __restrict__ bq, const float* __restrict__ bk,
                 const float* __restrict__ bv,
                 ushort_t* __restrict__ Yq, ushort_t* __restrict__ Yk,
                 ushort_t* __restrict__ Yv) {
  __shared__ __align__(16) ushort_t alds[32768];   // 64 frags x 1KB = 64KB
  const int z = blockIdx.y;
  const float*    X    = (z == 0) ? Xq : (z == 1) ? Xk : Xv;
  const ushort_t* Wpk  = (z == 0) ? Wqp : (z == 1) ? Wkp : Wvp;
  const float*    bias = (z == 0) ? bq : (z == 1) ? bk : bv;
  ushort_t*       Y    = (z == 0) ? Yq : (z == 1) ? Yk : Yv;
  const int t  = threadIdx.x;
  const int m0 = blockIdx.x * 64;

  // Stage A panel once: coalesced fp32 read (wave reads contiguous 2KB rows),
  // cvt, frag-packed ds_write. unit u = 32B of a row: row=u>>6, k8=u&63.
  #pragma unroll
  for (int it = 0; it < 16; ++it) {
    const int u   = it * 256 + t;        // 0..4095
    const int row = u >> 6;
    const int k8  = u & 63;
    const float4 x0 = *(const float4*)&X[(size_t)(m0 + row) * CDIM + k8 * 8];
    const float4 x1 = *(const float4*)&X[(size_t)(m0 + row) * CDIM + k8 * 8 + 4];
    short8_t v;
    v[0] = (short)f2bf(x0.x); v[1] = (short)f2bf(x0.y);
    v[2] = (short)f2bf(x0.z); v[3] = (short)f2bf(x0.w);
    v[4] = (short)f2bf(x1.x); v[5] = (short)f2bf(x1.y);
    v[6] = (short)f2bf(x1.z); v[7] = (short)f2bf(x1.w);
    const int kf = k8 >> 2, mf = row >> 4;
    const int ln = (k8 & 3) * 16 + (row & 15);
    *(short8_t*)&alds[((kf * 4 + mf) * 64 + ln) * 8] = v;
  }
  __syncthreads();   // the ONLY barrier

  nobar_compute<0>(alds, Wpk, bias, Y, z < 2, m0);
}

// Output projection: bf16 A staged via global_load_lds, fp32 out
__global__ __launch_bounds__(256)
void outp_nobar(const ushort_t* __restrict__ A, const ushort_t* __restrict__ Wpk,
                const float* __restrict__ bias, float* __restrict__ Y) {
  __shared__ __align__(16) ushort_t alds[32768];
  const int t    = threadIdx.x;
  const int w    = t >> 6;
  const int lane = t & 63;
  const int m0   = blockIdx.x * 64;

  // 64 frags, wave stages 16: frag fid = w*16+j, kf=fid>>2, mf=fid&3
  #pragma unroll
  for (int j = 0; j < 16; ++j) {
    const int fid = w * 16 + j;
    const int kf = fid >> 2, mf = fid & 3;
    const ushort_t* ga = A +
        (size_t)(m0 + mf * 16 + (lane & 15)) * CDIM + kf * 32 + (lane >> 4) * 8;
    gl2lds16(ga, (ushort_t*)&alds[fid * 512]);
  }
  __syncthreads();   // the ONLY barrier (drains vm+lgkm)

  nobar_compute<1>(alds, Wpk, bias, Y, false, m0);
}

// ---------------------------------------------------------------------------
// kv GEMM: per (b,h), kv[d][f] = sum_s k[s][d]*v[s][f], ksum[d] = sum_s k[s][d].
// Split-K: grid (32 bh, 16 chunks of 512 s). Reg-staged transpose into
// fragment-packed LDS (A = k^T, B = v); ksum via ones-B-fragment MFMA.
// ---------------------------------------------------------------------------
__global__ __launch_bounds__(256)
void gemm_kv(const ushort_t* __restrict__ Kb, const ushort_t* __restrict__ Vb,
             float* __restrict__ kvpart, float* __restrict__ ksumpart) {
  __shared__ __align__(16) ushort_t klds[8192];
  __shared__ __align__(16) ushort_t vlds[8192];
  const int bh    = blockIdx.x;
  const int chunk = blockIdx.y;
  const int b = bh >> 3, h = bh & 7;
  const int t = threadIdx.x;
  const int w = t >> 6;
  const int lane = t & 63;

  f32x4 acc[4];
  #pragma unroll
  for (int fg = 0; fg < 4; ++fg) acc[fg] = (f32x4){0.f, 0.f, 0.f, 0.f};
  f32x4 accs = (f32x4){0.f, 0.f, 0.f, 0.f};

  short8_t ones;
  #pragma unroll
  for (int i = 0; i < 8; ++i) ones[i] = (short)0x3F80;

  for (int round = 0; round < 4; ++round) {
    const int sbase = chunk * 512 + round * 128;
    __syncthreads();
    #pragma unroll
    for (int i = 0; i < 4; ++i) {
      const int idx  = i * 256 + t;
      const int sl   = idx >> 3;
      const int d8   = idx & 7;
      const size_t src = (size_t)((sbase + sl) * BATCH + b) * CDIM + h * DDIM + d8 * 8;
      const ushort8_t kp = *(const ushort8_t*)&Kb[src];
      const ushort8_t vp = *(const ushort8_t*)&Vb[src];
      const int sb  = sl >> 5;
      const int j   = sl & 7;
      const int lp0 = (d8 & 1) * 8 + ((sl >> 3) & 3) * 16;
      const int dg  = d8 >> 1;
      const int kbase = ((sb * 4 + dg) * 64 + lp0) * 8 + j;
      #pragma unroll
      for (int e = 0; e < 8; ++e) {
        klds[kbase + e * 8] = kp[e];
        vlds[kbase + e * 8] = vp[e];
      }
    }
    __syncthreads();
    #pragma unroll
    for (int sb = 0; sb < 4; ++sb) {
      const short8_t af = *(const short8_t*)&klds[((sb * 4 + w) * 64 + lane) * 8];
      accs = __builtin_amdgcn_mfma_f32_16x16x32_bf16(af, ones, accs, 0, 0, 0);
      #pragma unroll
      for (int fg = 0; fg < 4; ++fg) {
        const short8_t bf = *(const short8_t*)&vlds[((sb * 4 + fg) * 64 + lane) * 8];
        acc[fg] = __builtin_amdgcn_mfma_f32_16x16x32_bf16(af, bf, acc[fg], 0, 0, 0);
      }
    }
  }

  const size_t obase = ((size_t)bh * 16 + chunk) * 64;
  #pragma unroll
  for (int fg = 0; fg < 4; ++fg)
    #pragma unroll
    for (int r = 0; r < 4; ++r) {
      const int d = w * 16 + (lane >> 4) * 4 + r;
      kvpart[(obase + d) * 64 + fg * 16 + (lane & 15)] = acc[fg][r];
    }
  if ((lane & 15) == 0) {
    #pragma unroll
    for (int r = 0; r < 4; ++r)
      ksumpart[obase + w * 16 + (lane >> 4) * 4 + r] = accs[r];
  }
}

// ---------------------------------------------------------------------------
__global__ __launch_bounds__(256)
void kv_finish(const float* __restrict__ kvpart, const float* __restrict__ ksumpart,
               ushort_t* __restrict__ kvT) {
  const int bh = blockIdx.x;
  const int t  = threadIdx.x;
  for (int idx = t; idx < 4096; idx += 256) {
    const int d = idx >> 6, f = idx & 63;
    float s = 0.f;
    for (int c = 0; c < 16; ++c)
      s += kvpart[(((size_t)bh * 16 + c) * 64 + d) * 64 + f];
    kvT[((size_t)bh * 80 + f) * 64 + d] = f2bf(s);
  }
  if (t < 64) {
    float s = 0.f;
    for (int c = 0; c < 16; ++c)
      s += ksumpart[((size_t)bh * 16 + c) * 64 + t];
    kvT[((size_t)bh * 80 + 64) * 64 + t] = f2bf(s);
  }
  for (int i = t; i < 15 * 64; i += 256)
    kvT[((size_t)bh * 80 + 65) * 64 + i] = 0;
}

// ---------------------------------------------------------------------------
// qkv GEMM: y = (q @ kv) / (q . ksum + eps); B = kvT_pad [80][64], col 64 = denom.
// ---------------------------------------------------------------------------
__global__ __launch_bounds__(256)
void gemm_qkv(ushort_t* __restrict__ Qb, const ushort_t* __restrict__ kvT) {
  __shared__ __align__(16) ushort_t alds[8192];
  __shared__ __align__(16) ushort_t blds[5120];
  const int bh    = blockIdx.x;
  const int chunk = blockIdx.y;
  const int b = bh >> 3, h = bh & 7;
  const int t = threadIdx.x;
  const int w = t >> 6;
  const int lane = t & 63;
  const int lr = lane & 15;
  const int lk = (lane >> 4) * 8;

  #pragma unroll
  for (int i = 0; i < 4; ++i) {
    const int fidx = w * 4 + i;
    const int ks = fidx >> 3, fm = fidx & 7;
    const ushort_t* src = Qb +
        (size_t)((chunk * 128 + fm * 16 + lr) * BATCH + b) * CDIM +
        h * DDIM + ks * 32 + lk;
    gl2lds16(src, &alds[fidx * 512]);
  }
  for (int idx = w; idx < 10; idx += 4) {
    const int ks = idx / 5, fg = idx % 5;
    const ushort_t* src = kvT + (size_t)(bh * 80 + fg * 16 + lr) * 64 + ks * 32 + lk;
    gl2lds16(src, &blds[idx * 512]);
  }
  __syncthreads();

  f32x4 acc[2][5];
  #pragma unroll
  for (int mi = 0; mi < 2; ++mi)
    #pragma unroll
    for (int fg = 0; fg < 5; ++fg)
      acc[mi][fg] = (f32x4){0.f, 0.f, 0.f, 0.f};

  #pragma unroll
  for (int ks = 0; ks < 2; ++ks) {
    short8_t af[2], bf[5];
    #pragma unroll
    for (int mi = 0; mi < 2; ++mi)
      af[mi] = *(const short8_t*)&alds[(ks * 8 + w * 2 + mi) * 512 + lane * 8];
    #pragma unroll
    for (int fg = 0; fg < 5; ++fg)
      bf[fg] = *(const short8_t*)&blds[(ks * 5 + fg) * 512 + lane * 8];
    #pragma unroll
    for (int mi = 0; mi < 2; ++mi)
      #pragma unroll
      for (int fg = 0; fg < 5; ++fg)
        acc[mi][fg] = __builtin_amdgcn_mfma_f32_16x16x32_bf16(
            af[mi], bf[fg], acc[mi][fg], 0, 0, 0);
  }

  #pragma unroll
  for (int mi = 0; mi < 2; ++mi) {
    #pragma unroll
    for (int r = 0; r < 4; ++r) {
      const float dv  = __shfl(acc[mi][4][r], lane & 48);
      const float inv = 1.f / (dv + EPS_F);
      const int s = chunk * 128 + w * 32 + mi * 16 + (lane >> 4) * 4 + r;
      const size_t rowb = (size_t)(s * BATCH + b) * CDIM + h * DDIM;
      #pragma unroll
      for (int fg = 0; fg < 4; ++fg)
        Qb[rowb + fg * 16 + lr] = f2bf(acc[mi][fg][r] * inv);
    }
  }
}

// ---------------------------------------------------------------------------
extern "C" void kernel_launch(void* const* d_in, const int* in_sizes, int n_in,
                              void* d_out, int out_size, void* d_ws, size_t ws_size,
                              hipStream_t stream) {
  const float* q_in = (const float*)d_in[0];
  const float* k_in = (const float*)d_in[1];
  const float* v_in = (const float*)d_in[2];
  const float* Wq   = (const float*)d_in[3];
  const float* bq   = (const float*)d_in[4];
  const float* Wk   = (const float*)d_in[5];
  const float* bk   = (const float*)d_in[6];
  const float* Wv   = (const float*)d_in[7];
  const float* bv   = (const float*)d_in[8];
  const float* Wp   = (const float*)d_in[9];
  const float* bp   = (const float*)d_in[10];
  float* out = (float*)d_out;

  const size_t NTOK = (size_t)MROWS * CDIM;      // 16,777,216 elems
  const size_t NW   = (size_t)CDIM * CDIM;       // 262,144
  ushort_t* Wqp    = (ushort_t*)d_ws;            // fragment-packed bf16 weights
  ushort_t* Wkp    = Wqp + NW;
  ushort_t* Wvp    = Wkp + NW;
  ushort_t* Wpp    = Wvp + NW;
  ushort_t* qbuf   = Wpp + NW;
  ushort_t* kbuf   = qbuf + NTOK;
  ushort_t* vbuf   = kbuf + NTOK;
  ushort_t* kvT    = vbuf + NTOK;                           // 32*80*64
  float* kvpart    = (float*)(kvT + (size_t)32 * 80 * 64);  // 512*64*64
  float* ksumpart  = kvpart + (size_t)512 * 64 * 64;        // 512*64

  const dim3 blk(256);

  // 1) Weights fp32 -> bf16, fragment-packed
  cvtW_pack<<<dim3(128, 4), blk, 0, stream>>>(Wq, Wk, Wv, Wp,
                                              Wqp, Wkp, Wvp, Wpp);

  // 2) Q/K/V projections: barrier-free main loop (A staged once per block)
  proj3_nobar<<<dim3(MROWS / 64, 3), blk, 0, stream>>>(
      q_in, k_in, v_in, Wqp, Wkp, Wvp, bq, bk, bv, qbuf, kbuf, vbuf);

  // 3) kv = sum_s k^T v (+ ksum via ones-MFMA), split-K then finish
  gemm_kv<<<dim3(32, 16), blk, 0, stream>>>(kbuf, vbuf, kvpart, ksumpart);
  kv_finish<<<dim3(32), blk, 0, stream>>>(kvpart, ksumpart, kvT);

  // 4) y = (q @ kv) / (q . ksum + eps), bf16 in place over q buffer
  gemm_qkv<<<dim3(32, 64), blk, 0, stream>>>(qbuf, kvT);

  // 5) Output projection: barrier-free, bf16 A via DMA -> fp32 d_out
  outp_nobar<<<dim3(MROWS / 64), blk, 0, stream>>>(qbuf, Wpp, bp, out);
}